// Round 1
// baseline (3997.171 us; speedup 1.0000x reference)
//
#include <hip/hip_runtime.h>
#include <cmath>

#define E_ 64
#define H_ 4
#define B_ 2
#define R_ 1225
#define C_ 512
#define EPS 1e-5f

__device__ __forceinline__ float elu1(float a) { return a > 0.f ? a + 1.f : __expf(a); }

// ---------------------------------------------------------------------------
// Kernel A: row attention over c (length C) for each (b, r).
// Reads x in (B,E,R,C); writes h in (B,C,R,E).
// ---------------------------------------------------------------------------
__global__ __launch_bounds__(512) void row_attn(
    const float* __restrict__ x,
    const float* __restrict__ wq, const float* __restrict__ bq,
    const float* __restrict__ wk, const float* __restrict__ bk,
    const float* __restrict__ wv, const float* __restrict__ bv,
    const float* __restrict__ wo, const float* __restrict__ bo,
    const float* __restrict__ lng, const float* __restrict__ lnb,
    float* __restrict__ hout)
{
    const int r = blockIdx.x;
    const int b = blockIdx.y;
    const int c = threadIdx.x;
    const int wid = threadIdx.x >> 6;
    const int lane = threadIdx.x & 63;

    __shared__ float red_u[8][H_][E_];
    __shared__ float red_q[8][H_];
    __shared__ float red_k[8][H_];
    __shared__ float s_u[H_][E_];
    __shared__ float s_sk[H_];
    __shared__ float s_qm[H_];
    __shared__ float s_ktv[E_];
    __shared__ float s_wok[E_][H_];

    // load x[b, :, r, c] (coalesced across threads for each e)
    float xv[E_];
    {
        const size_t ec = (size_t)R_ * C_;
        const float* xp = x + (size_t)b * E_ * ec + (size_t)r * C_ + c;
        #pragma unroll
        for (int e = 0; e < E_; ++e) xv[e] = xp[(size_t)e * ec];
    }
    // LayerNorm over E
    float s = 0.f, ss = 0.f;
    #pragma unroll
    for (int e = 0; e < E_; ++e) { s += xv[e]; ss += xv[e] * xv[e]; }
    const float mu = s * (1.f / E_);
    const float rstd = rsqrtf(ss * (1.f / E_) - mu * mu + EPS);
    float xn[E_];
    #pragma unroll
    for (int e = 0; e < E_; ++e) xn[e] = (xv[e] - mu) * rstd * lng[e] + lnb[e];

    // q, k heads
    float q[H_], k[H_];
    #pragma unroll
    for (int h = 0; h < H_; ++h) {
        float aq = bq[h], ak = bk[h];
        #pragma unroll
        for (int e = 0; e < E_; ++e) { aq += xn[e] * wq[h * E_ + e]; ak += xn[e] * wk[h * E_ + e]; }
        q[h] = elu1(aq); k[h] = elu1(ak);
    }

    // u[h][e] = sum_c k[h,c]*xn[c,e]  (wave butterfly all-reduce, keep slot lane==e)
    float au[H_] = {0.f, 0.f, 0.f, 0.f};
    #pragma unroll
    for (int h = 0; h < H_; ++h) {
        #pragma unroll
        for (int e = 0; e < E_; ++e) {
            float t = k[h] * xn[e];
            #pragma unroll
            for (int off = 32; off; off >>= 1) t += __shfl_xor(t, off, 64);
            if (lane == e) au[h] = t;
        }
    }
    #pragma unroll
    for (int h = 0; h < H_; ++h) {
        red_u[wid][h][lane] = au[h];
        float tq = q[h], tk = k[h];
        #pragma unroll
        for (int off = 32; off; off >>= 1) { tq += __shfl_xor(tq, off, 64); tk += __shfl_xor(tk, off, 64); }
        if (lane == 0) { red_q[wid][h] = tq; red_k[wid][h] = tk; }
    }
    __syncthreads();
    if (threadIdx.x < H_ * E_) {
        const int h = threadIdx.x >> 6, e = threadIdx.x & 63;
        float t = 0.f;
        #pragma unroll
        for (int w = 0; w < 8; ++w) t += red_u[w][h][e];
        s_u[h][e] = t;
        if (e == 0) {
            float sq = 0.f, sk = 0.f;
            #pragma unroll
            for (int w = 0; w < 8; ++w) { sq += red_q[w][h]; sk += red_k[w][h]; }
            s_sk[h] = sk;
            s_qm[h] = sq * (1.f / C_);
        }
    }
    __syncthreads();
    // ktv[j] = dot(wv[j], u[h])/sk[h] + bv[j]
    if (threadIdx.x < E_) {
        const int j = threadIdx.x, h = j >> 4;
        float t = 0.f;
        #pragma unroll
        for (int e = 0; e < E_; ++e) t += wv[j * E_ + e] * s_u[h][e];
        s_ktv[j] = t / s_sk[h] + bv[j];
    }
    __syncthreads();
    // wok[e][h] = sum_d wo[e][h*16+d]*ktv[h*16+d]
    if (threadIdx.x < E_) {
        const int e = threadIdx.x;
        #pragma unroll
        for (int h = 0; h < H_; ++h) {
            float t = 0.f;
            #pragma unroll
            for (int d = 0; d < 16; ++d) t += wo[e * E_ + h * 16 + d] * s_ktv[h * 16 + d];
            s_wok[e][h] = t;
        }
    }
    __syncthreads();

    float qn[H_];
    #pragma unroll
    for (int h = 0; h < H_; ++h) qn[h] = q[h] / s_qm[h];

    float* hp = hout + ((size_t)(b * C_ + c) * R_ + r) * E_;
    #pragma unroll
    for (int e4 = 0; e4 < 16; ++e4) {
        float4 o;
        float* ov = (float*)&o;
        #pragma unroll
        for (int i = 0; i < 4; ++i) {
            const int e = e4 * 4 + i;
            float t = bo[e];
            #pragma unroll
            for (int h = 0; h < H_; ++h) t += qn[h] * s_wok[e][h];
            ov[i] = xv[e] + t;
        }
        *reinterpret_cast<float4*>(hp + e4 * 4) = o;
    }
}

// ---------------------------------------------------------------------------
// Kernel B: col attention over r (length R) for each (b, c). In-place on h.
// ---------------------------------------------------------------------------
__global__ __launch_bounds__(256) void col_attn(
    float* __restrict__ hbuf,
    const float* __restrict__ wq, const float* __restrict__ bq,
    const float* __restrict__ wk, const float* __restrict__ bk,
    const float* __restrict__ wv, const float* __restrict__ bv,
    const float* __restrict__ wo, const float* __restrict__ bo,
    const float* __restrict__ lng, const float* __restrict__ lnb)
{
    const int c = blockIdx.x;
    const int b = blockIdx.y;
    const int wid = threadIdx.x >> 6;
    const int lane = threadIdx.x & 63;
    float* hp = hbuf + (size_t)(b * C_ + c) * R_ * E_;

    __shared__ float red_u[4][H_][E_];
    __shared__ float red_q[4][H_];
    __shared__ float red_k[4][H_];
    __shared__ float s_u[H_][E_];
    __shared__ float s_sk[H_];
    __shared__ float s_qm[H_];
    __shared__ float s_ktv[E_];
    __shared__ float s_wok[E_][H_];

    float au[H_] = {0.f, 0.f, 0.f, 0.f};
    float aq[H_] = {0.f, 0.f, 0.f, 0.f};
    float ak[H_] = {0.f, 0.f, 0.f, 0.f};

    // pass 1: accumulate u, sum_q, sum_k
    #pragma unroll 1
    for (int it = 0; it < 5; ++it) {
        const int r = threadIdx.x + it * 256;
        float xn[E_];
        float q[H_], k[H_];
        if (r < R_) {
            const float* pp = hp + (size_t)r * E_;
            float hv[E_];
            #pragma unroll
            for (int e4 = 0; e4 < 16; ++e4) {
                const float4 v4 = *reinterpret_cast<const float4*>(pp + e4 * 4);
                hv[e4 * 4 + 0] = v4.x; hv[e4 * 4 + 1] = v4.y;
                hv[e4 * 4 + 2] = v4.z; hv[e4 * 4 + 3] = v4.w;
            }
            float s = 0.f, ss = 0.f;
            #pragma unroll
            for (int e = 0; e < E_; ++e) { s += hv[e]; ss += hv[e] * hv[e]; }
            const float mu = s * (1.f / E_);
            const float rstd = rsqrtf(ss * (1.f / E_) - mu * mu + EPS);
            #pragma unroll
            for (int e = 0; e < E_; ++e) xn[e] = (hv[e] - mu) * rstd * lng[e] + lnb[e];
            #pragma unroll
            for (int h = 0; h < H_; ++h) {
                float tq = bq[h], tk = bk[h];
                #pragma unroll
                for (int e = 0; e < E_; ++e) { tq += xn[e] * wq[h * E_ + e]; tk += xn[e] * wk[h * E_ + e]; }
                q[h] = elu1(tq); k[h] = elu1(tk);
                aq[h] += q[h]; ak[h] += k[h];
            }
        } else {
            #pragma unroll
            for (int e = 0; e < E_; ++e) xn[e] = 0.f;
            #pragma unroll
            for (int h = 0; h < H_; ++h) { q[h] = 0.f; k[h] = 0.f; }
        }
        #pragma unroll
        for (int h = 0; h < H_; ++h) {
            #pragma unroll
            for (int e = 0; e < E_; ++e) {
                float t = k[h] * xn[e];
                #pragma unroll
                for (int off = 32; off; off >>= 1) t += __shfl_xor(t, off, 64);
                if (lane == e) au[h] += t;
            }
        }
    }
    #pragma unroll
    for (int h = 0; h < H_; ++h) {
        red_u[wid][h][lane] = au[h];
        float tq = aq[h], tk = ak[h];
        #pragma unroll
        for (int off = 32; off; off >>= 1) { tq += __shfl_xor(tq, off, 64); tk += __shfl_xor(tk, off, 64); }
        if (lane == 0) { red_q[wid][h] = tq; red_k[wid][h] = tk; }
    }
    __syncthreads();
    if (threadIdx.x < H_ * E_) {
        const int h = threadIdx.x >> 6, e = threadIdx.x & 63;
        float t = 0.f;
        #pragma unroll
        for (int w = 0; w < 4; ++w) t += red_u[w][h][e];
        s_u[h][e] = t;
        if (e == 0) {
            float sq = 0.f, sk = 0.f;
            #pragma unroll
            for (int w = 0; w < 4; ++w) { sq += red_q[w][h]; sk += red_k[w][h]; }
            s_sk[h] = sk;
            s_qm[h] = sq * (1.f / R_);
        }
    }
    __syncthreads();
    if (threadIdx.x < E_) {
        const int j = threadIdx.x, h = j >> 4;
        float t = 0.f;
        #pragma unroll
        for (int e = 0; e < E_; ++e) t += wv[j * E_ + e] * s_u[h][e];
        s_ktv[j] = t / s_sk[h] + bv[j];
    }
    __syncthreads();
    if (threadIdx.x < E_) {
        const int e = threadIdx.x;
        #pragma unroll
        for (int h = 0; h < H_; ++h) {
            float t = 0.f;
            #pragma unroll
            for (int d = 0; d < 16; ++d) t += wo[e * E_ + h * 16 + d] * s_ktv[h * 16 + d];
            s_wok[e][h] = t;
        }
    }
    __syncthreads();

    // pass 2: apply attention + residual, in place
    #pragma unroll 1
    for (int it = 0; it < 5; ++it) {
        const int r = threadIdx.x + it * 256;
        if (r >= R_) continue;
        float* pp = hp + (size_t)r * E_;
        float hv[E_];
        #pragma unroll
        for (int e4 = 0; e4 < 16; ++e4) {
            const float4 v4 = *reinterpret_cast<const float4*>(pp + e4 * 4);
            hv[e4 * 4 + 0] = v4.x; hv[e4 * 4 + 1] = v4.y;
            hv[e4 * 4 + 2] = v4.z; hv[e4 * 4 + 3] = v4.w;
        }
        float s = 0.f, ss = 0.f;
        #pragma unroll
        for (int e = 0; e < E_; ++e) { s += hv[e]; ss += hv[e] * hv[e]; }
        const float mu = s * (1.f / E_);
        const float rstd = rsqrtf(ss * (1.f / E_) - mu * mu + EPS);
        float tq0 = bq[0], tq1 = bq[1], tq2 = bq[2], tq3 = bq[3];
        #pragma unroll
        for (int e = 0; e < E_; ++e) {
            const float xne = (hv[e] - mu) * rstd * lng[e] + lnb[e];
            tq0 += xne * wq[0 * E_ + e];
            tq1 += xne * wq[1 * E_ + e];
            tq2 += xne * wq[2 * E_ + e];
            tq3 += xne * wq[3 * E_ + e];
        }
        float qn[H_];
        qn[0] = elu1(tq0) / s_qm[0];
        qn[1] = elu1(tq1) / s_qm[1];
        qn[2] = elu1(tq2) / s_qm[2];
        qn[3] = elu1(tq3) / s_qm[3];
        #pragma unroll
        for (int e4 = 0; e4 < 16; ++e4) {
            float4 o;
            float* ov = (float*)&o;
            #pragma unroll
            for (int i = 0; i < 4; ++i) {
                const int e = e4 * 4 + i;
                float t = bo[e];
                #pragma unroll
                for (int h = 0; h < H_; ++h) t += qn[h] * s_wok[e][h];
                ov[i] = hv[e] + t;
            }
            *reinterpret_cast<float4*>(pp + e4 * 4) = o;
        }
    }
}

// ---------------------------------------------------------------------------
// Kernel C: per-position FFN (LN -> 256 GELU -> 64) + residual; writes output
// transposed to (B,E,R,C) with coalesced stores (threads adjacent in c).
// ---------------------------------------------------------------------------
__global__ __launch_bounds__(256) void ffn_kernel(
    const float* __restrict__ hbuf,
    const float* __restrict__ lng, const float* __restrict__ lnb,
    const float* __restrict__ w1, const float* __restrict__ b1,
    const float* __restrict__ w2, const float* __restrict__ b2,
    float* __restrict__ out)
{
    __shared__ float w2t[256][E_ + 4];   // transposed w2, padded for banks+alignment
    for (int i = threadIdx.x; i < 256 * E_; i += 256) {
        const int e = i >> 8, j = i & 255;
        w2t[j][e] = w2[i];
    }
    __syncthreads();

    const int p = blockIdx.x * 256 + threadIdx.x;
    const int c = p & (C_ - 1);
    const int t2 = p >> 9;
    const int r = t2 % R_;
    const int b = t2 / R_;

    const float* pp = hbuf + ((size_t)(b * C_ + c) * R_ + r) * E_;
    float hv[E_];
    #pragma unroll
    for (int e4 = 0; e4 < 16; ++e4) {
        const float4 v4 = *reinterpret_cast<const float4*>(pp + e4 * 4);
        hv[e4 * 4 + 0] = v4.x; hv[e4 * 4 + 1] = v4.y;
        hv[e4 * 4 + 2] = v4.z; hv[e4 * 4 + 3] = v4.w;
    }
    float s = 0.f, ss = 0.f;
    #pragma unroll
    for (int e = 0; e < E_; ++e) { s += hv[e]; ss += hv[e] * hv[e]; }
    const float mu = s * (1.f / E_);
    const float rstd = rsqrtf(ss * (1.f / E_) - mu * mu + EPS);
    float xn[E_];
    #pragma unroll
    for (int e = 0; e < E_; ++e) xn[e] = (hv[e] - mu) * rstd * lng[e] + lnb[e];
    float acc[E_];
    #pragma unroll
    for (int e = 0; e < E_; ++e) acc[e] = hv[e] + b2[e];

    #pragma unroll 1
    for (int j = 0; j < 256; ++j) {
        float a = b1[j];
        #pragma unroll
        for (int e = 0; e < E_; ++e) a += xn[e] * w1[j * E_ + e];
        const float gl = 0.5f * a * (1.f + erff(a * 0.70710678118654752f));
        const float4* wrow = reinterpret_cast<const float4*>(&w2t[j][0]);
        #pragma unroll
        for (int e4 = 0; e4 < 16; ++e4) {
            const float4 w4 = wrow[e4];
            acc[e4 * 4 + 0] += w4.x * gl;
            acc[e4 * 4 + 1] += w4.y * gl;
            acc[e4 * 4 + 2] += w4.z * gl;
            acc[e4 * 4 + 3] += w4.w * gl;
        }
    }

    float* op = out + ((size_t)(b * E_) * R_ + r) * C_ + c;
    const size_t es = (size_t)R_ * C_;
    #pragma unroll
    for (int e = 0; e < E_; ++e) op[(size_t)e * es] = acc[e];
}

extern "C" void kernel_launch(void* const* d_in, const int* in_sizes, int n_in,
                              void* d_out, int out_size, void* d_ws, size_t ws_size,
                              hipStream_t stream) {
    const float* x      = (const float*)d_in[0];
    const float* row_wq = (const float*)d_in[1];
    const float* row_bq = (const float*)d_in[2];
    const float* row_wk = (const float*)d_in[3];
    const float* row_bk = (const float*)d_in[4];
    const float* row_wv = (const float*)d_in[5];
    const float* row_bv = (const float*)d_in[6];
    const float* row_wo = (const float*)d_in[7];
    const float* row_bo = (const float*)d_in[8];
    const float* col_wq = (const float*)d_in[9];
    const float* col_bq = (const float*)d_in[10];
    const float* col_wk = (const float*)d_in[11];
    const float* col_bk = (const float*)d_in[12];
    const float* col_wv = (const float*)d_in[13];
    const float* col_bv = (const float*)d_in[14];
    const float* col_wo = (const float*)d_in[15];
    const float* col_bo = (const float*)d_in[16];
    const float* rn_g   = (const float*)d_in[17];
    const float* rn_b   = (const float*)d_in[18];
    const float* cn_g   = (const float*)d_in[19];
    const float* cn_b   = (const float*)d_in[20];
    const float* fn_g   = (const float*)d_in[21];
    const float* fn_b   = (const float*)d_in[22];
    const float* w1     = (const float*)d_in[23];
    const float* b1     = (const float*)d_in[24];
    const float* w2     = (const float*)d_in[25];
    const float* b2     = (const float*)d_in[26];

    const size_t need = (size_t)B_ * C_ * R_ * E_ * sizeof(float);
    if (ws_size < need) return;  // workspace too small; fail loudly via validation
    float* hbuf = (float*)d_ws;

    row_attn<<<dim3(R_, B_), 512, 0, stream>>>(
        x, row_wq, row_bq, row_wk, row_bk, row_wv, row_bv, row_wo, row_bo,
        rn_g, rn_b, hbuf);
    col_attn<<<dim3(C_, B_), 256, 0, stream>>>(
        hbuf, col_wq, col_bq, col_wk, col_bk, col_wv, col_bv, col_wo, col_bo,
        cn_g, cn_b);
    ffn_kernel<<<(B_ * R_ * C_) / 256, 256, 0, stream>>>(
        hbuf, fn_g, fn_b, w1, b1, w2, b2, (float*)d_out);
}

// Round 2
// 2112.970 us; speedup vs baseline: 1.8917x; 1.8917x over previous
//
#include <hip/hip_runtime.h>
#include <cmath>

#define E_ 64
#define H_ 4
#define B_ 2
#define R_ 1225
#define C_ 512
#define EPS 1e-5f

__device__ __forceinline__ float elu1(float a) { return a > 0.f ? a + 1.f : __expf(a); }

typedef float f32x4 __attribute__((ext_vector_type(4)));
typedef short bf16x8 __attribute__((ext_vector_type(8)));

__device__ __forceinline__ unsigned short f2bf(float f) {
    union { float f; unsigned u; } c; c.f = f;
    unsigned u = c.u + 0x7FFFu + ((c.u >> 16) & 1u);   // RNE
    return (unsigned short)(u >> 16);
}

__device__ __forceinline__ bf16x8 pack8(float4 a, float4 b) {
    bf16x8 r;
    r[0] = (short)f2bf(a.x); r[1] = (short)f2bf(a.y);
    r[2] = (short)f2bf(a.z); r[3] = (short)f2bf(a.w);
    r[4] = (short)f2bf(b.x); r[5] = (short)f2bf(b.y);
    r[6] = (short)f2bf(b.z); r[7] = (short)f2bf(b.w);
    return r;
}

// ---------------------------------------------------------------------------
// Kernel A: row attention over c (length C) for each (b, r).
// Reads x in (B,E,R,C); writes h in (B,C,R,E).   (unchanged from round 1)
// ---------------------------------------------------------------------------
__global__ __launch_bounds__(512) void row_attn(
    const float* __restrict__ x,
    const float* __restrict__ wq, const float* __restrict__ bq,
    const float* __restrict__ wk, const float* __restrict__ bk,
    const float* __restrict__ wv, const float* __restrict__ bv,
    const float* __restrict__ wo, const float* __restrict__ bo,
    const float* __restrict__ lng, const float* __restrict__ lnb,
    float* __restrict__ hout)
{
    const int r = blockIdx.x;
    const int b = blockIdx.y;
    const int c = threadIdx.x;
    const int wid = threadIdx.x >> 6;
    const int lane = threadIdx.x & 63;

    __shared__ float red_u[8][H_][E_];
    __shared__ float red_q[8][H_];
    __shared__ float red_k[8][H_];
    __shared__ float s_u[H_][E_];
    __shared__ float s_sk[H_];
    __shared__ float s_qm[H_];
    __shared__ float s_ktv[E_];
    __shared__ float s_wok[E_][H_];

    float xv[E_];
    {
        const size_t ec = (size_t)R_ * C_;
        const float* xp = x + (size_t)b * E_ * ec + (size_t)r * C_ + c;
        #pragma unroll
        for (int e = 0; e < E_; ++e) xv[e] = xp[(size_t)e * ec];
    }
    float s = 0.f, ss = 0.f;
    #pragma unroll
    for (int e = 0; e < E_; ++e) { s += xv[e]; ss += xv[e] * xv[e]; }
    const float mu = s * (1.f / E_);
    const float rstd = rsqrtf(ss * (1.f / E_) - mu * mu + EPS);
    float xn[E_];
    #pragma unroll
    for (int e = 0; e < E_; ++e) xn[e] = (xv[e] - mu) * rstd * lng[e] + lnb[e];

    float q[H_], k[H_];
    #pragma unroll
    for (int h = 0; h < H_; ++h) {
        float aq = bq[h], ak = bk[h];
        #pragma unroll
        for (int e = 0; e < E_; ++e) { aq += xn[e] * wq[h * E_ + e]; ak += xn[e] * wk[h * E_ + e]; }
        q[h] = elu1(aq); k[h] = elu1(ak);
    }

    float au[H_] = {0.f, 0.f, 0.f, 0.f};
    #pragma unroll
    for (int h = 0; h < H_; ++h) {
        #pragma unroll
        for (int e = 0; e < E_; ++e) {
            float t = k[h] * xn[e];
            #pragma unroll
            for (int off = 32; off; off >>= 1) t += __shfl_xor(t, off, 64);
            if (lane == e) au[h] = t;
        }
    }
    #pragma unroll
    for (int h = 0; h < H_; ++h) {
        red_u[wid][h][lane] = au[h];
        float tq = q[h], tk = k[h];
        #pragma unroll
        for (int off = 32; off; off >>= 1) { tq += __shfl_xor(tq, off, 64); tk += __shfl_xor(tk, off, 64); }
        if (lane == 0) { red_q[wid][h] = tq; red_k[wid][h] = tk; }
    }
    __syncthreads();
    if (threadIdx.x < H_ * E_) {
        const int h = threadIdx.x >> 6, e = threadIdx.x & 63;
        float t = 0.f;
        #pragma unroll
        for (int w = 0; w < 8; ++w) t += red_u[w][h][e];
        s_u[h][e] = t;
        if (e == 0) {
            float sq = 0.f, sk = 0.f;
            #pragma unroll
            for (int w = 0; w < 8; ++w) { sq += red_q[w][h]; sk += red_k[w][h]; }
            s_sk[h] = sk;
            s_qm[h] = sq * (1.f / C_);
        }
    }
    __syncthreads();
    if (threadIdx.x < E_) {
        const int j = threadIdx.x, h = j >> 4;
        float t = 0.f;
        #pragma unroll
        for (int e = 0; e < E_; ++e) t += wv[j * E_ + e] * s_u[h][e];
        s_ktv[j] = t / s_sk[h] + bv[j];
    }
    __syncthreads();
    if (threadIdx.x < E_) {
        const int e = threadIdx.x;
        #pragma unroll
        for (int h = 0; h < H_; ++h) {
            float t = 0.f;
            #pragma unroll
            for (int d = 0; d < 16; ++d) t += wo[e * E_ + h * 16 + d] * s_ktv[h * 16 + d];
            s_wok[e][h] = t;
        }
    }
    __syncthreads();

    float qn[H_];
    #pragma unroll
    for (int h = 0; h < H_; ++h) qn[h] = q[h] / s_qm[h];

    float* hp = hout + ((size_t)(b * C_ + c) * R_ + r) * E_;
    #pragma unroll
    for (int e4 = 0; e4 < 16; ++e4) {
        float4 o;
        float* ov = (float*)&o;
        #pragma unroll
        for (int i = 0; i < 4; ++i) {
            const int e = e4 * 4 + i;
            float t = bo[e];
            #pragma unroll
            for (int h = 0; h < H_; ++h) t += qn[h] * s_wok[e][h];
            ov[i] = xv[e] + t;
        }
        *reinterpret_cast<float4*>(hp + e4 * 4) = o;
    }
}

// ---------------------------------------------------------------------------
// Kernel B: col attention over r (length R) for each (b, c). In-place on h.
// (unchanged from round 1)
// ---------------------------------------------------------------------------
__global__ __launch_bounds__(256) void col_attn(
    float* __restrict__ hbuf,
    const float* __restrict__ wq, const float* __restrict__ bq,
    const float* __restrict__ wk, const float* __restrict__ bk,
    const float* __restrict__ wv, const float* __restrict__ bv,
    const float* __restrict__ wo, const float* __restrict__ bo,
    const float* __restrict__ lng, const float* __restrict__ lnb)
{
    const int c = blockIdx.x;
    const int b = blockIdx.y;
    const int wid = threadIdx.x >> 6;
    const int lane = threadIdx.x & 63;
    float* hp = hbuf + (size_t)(b * C_ + c) * R_ * E_;

    __shared__ float red_u[4][H_][E_];
    __shared__ float red_q[4][H_];
    __shared__ float red_k[4][H_];
    __shared__ float s_u[H_][E_];
    __shared__ float s_sk[H_];
    __shared__ float s_qm[H_];
    __shared__ float s_ktv[E_];
    __shared__ float s_wok[E_][H_];

    float au[H_] = {0.f, 0.f, 0.f, 0.f};
    float aq[H_] = {0.f, 0.f, 0.f, 0.f};
    float ak[H_] = {0.f, 0.f, 0.f, 0.f};

    #pragma unroll 1
    for (int it = 0; it < 5; ++it) {
        const int r = threadIdx.x + it * 256;
        float xn[E_];
        float q[H_], k[H_];
        if (r < R_) {
            const float* pp = hp + (size_t)r * E_;
            float hv[E_];
            #pragma unroll
            for (int e4 = 0; e4 < 16; ++e4) {
                const float4 v4 = *reinterpret_cast<const float4*>(pp + e4 * 4);
                hv[e4 * 4 + 0] = v4.x; hv[e4 * 4 + 1] = v4.y;
                hv[e4 * 4 + 2] = v4.z; hv[e4 * 4 + 3] = v4.w;
            }
            float s = 0.f, ss = 0.f;
            #pragma unroll
            for (int e = 0; e < E_; ++e) { s += hv[e]; ss += hv[e] * hv[e]; }
            const float mu = s * (1.f / E_);
            const float rstd = rsqrtf(ss * (1.f / E_) - mu * mu + EPS);
            #pragma unroll
            for (int e = 0; e < E_; ++e) xn[e] = (hv[e] - mu) * rstd * lng[e] + lnb[e];
            #pragma unroll
            for (int h = 0; h < H_; ++h) {
                float tq = bq[h], tk = bk[h];
                #pragma unroll
                for (int e = 0; e < E_; ++e) { tq += xn[e] * wq[h * E_ + e]; tk += xn[e] * wk[h * E_ + e]; }
                q[h] = elu1(tq); k[h] = elu1(tk);
                aq[h] += q[h]; ak[h] += k[h];
            }
        } else {
            #pragma unroll
            for (int e = 0; e < E_; ++e) xn[e] = 0.f;
            #pragma unroll
            for (int h = 0; h < H_; ++h) { q[h] = 0.f; k[h] = 0.f; }
        }
        #pragma unroll
        for (int h = 0; h < H_; ++h) {
            #pragma unroll
            for (int e = 0; e < E_; ++e) {
                float t = k[h] * xn[e];
                #pragma unroll
                for (int off = 32; off; off >>= 1) t += __shfl_xor(t, off, 64);
                if (lane == e) au[h] += t;
            }
        }
    }
    #pragma unroll
    for (int h = 0; h < H_; ++h) {
        red_u[wid][h][lane] = au[h];
        float tq = aq[h], tk = ak[h];
        #pragma unroll
        for (int off = 32; off; off >>= 1) { tq += __shfl_xor(tq, off, 64); tk += __shfl_xor(tk, off, 64); }
        if (lane == 0) { red_q[wid][h] = tq; red_k[wid][h] = tk; }
    }
    __syncthreads();
    if (threadIdx.x < H_ * E_) {
        const int h = threadIdx.x >> 6, e = threadIdx.x & 63;
        float t = 0.f;
        #pragma unroll
        for (int w = 0; w < 4; ++w) t += red_u[w][h][e];
        s_u[h][e] = t;
        if (e == 0) {
            float sq = 0.f, sk = 0.f;
            #pragma unroll
            for (int w = 0; w < 4; ++w) { sq += red_q[w][h]; sk += red_k[w][h]; }
            s_sk[h] = sk;
            s_qm[h] = sq * (1.f / R_);
        }
    }
    __syncthreads();
    if (threadIdx.x < E_) {
        const int j = threadIdx.x, h = j >> 4;
        float t = 0.f;
        #pragma unroll
        for (int e = 0; e < E_; ++e) t += wv[j * E_ + e] * s_u[h][e];
        s_ktv[j] = t / s_sk[h] + bv[j];
    }
    __syncthreads();
    if (threadIdx.x < E_) {
        const int e = threadIdx.x;
        #pragma unroll
        for (int h = 0; h < H_; ++h) {
            float t = 0.f;
            #pragma unroll
            for (int d = 0; d < 16; ++d) t += wo[e * E_ + h * 16 + d] * s_ktv[h * 16 + d];
            s_wok[e][h] = t;
        }
    }
    __syncthreads();

    #pragma unroll 1
    for (int it = 0; it < 5; ++it) {
        const int r = threadIdx.x + it * 256;
        if (r >= R_) continue;
        float* pp = hp + (size_t)r * E_;
        float hv[E_];
        #pragma unroll
        for (int e4 = 0; e4 < 16; ++e4) {
            const float4 v4 = *reinterpret_cast<const float4*>(pp + e4 * 4);
            hv[e4 * 4 + 0] = v4.x; hv[e4 * 4 + 1] = v4.y;
            hv[e4 * 4 + 2] = v4.z; hv[e4 * 4 + 3] = v4.w;
        }
        float s = 0.f, ss = 0.f;
        #pragma unroll
        for (int e = 0; e < E_; ++e) { s += hv[e]; ss += hv[e] * hv[e]; }
        const float mu = s * (1.f / E_);
        const float rstd = rsqrtf(ss * (1.f / E_) - mu * mu + EPS);
        float tq0 = bq[0], tq1 = bq[1], tq2 = bq[2], tq3 = bq[3];
        #pragma unroll
        for (int e = 0; e < E_; ++e) {
            const float xne = (hv[e] - mu) * rstd * lng[e] + lnb[e];
            tq0 += xne * wq[0 * E_ + e];
            tq1 += xne * wq[1 * E_ + e];
            tq2 += xne * wq[2 * E_ + e];
            tq3 += xne * wq[3 * E_ + e];
        }
        float qn[H_];
        qn[0] = elu1(tq0) / s_qm[0];
        qn[1] = elu1(tq1) / s_qm[1];
        qn[2] = elu1(tq2) / s_qm[2];
        qn[3] = elu1(tq3) / s_qm[3];
        #pragma unroll
        for (int e4 = 0; e4 < 16; ++e4) {
            float4 o;
            float* ov = (float*)&o;
            #pragma unroll
            for (int i = 0; i < 4; ++i) {
                const int e = e4 * 4 + i;
                float t = bo[e];
                #pragma unroll
                for (int h = 0; h < H_; ++h) t += qn[h] * s_wok[e][h];
                ov[i] = hv[e] + t;
            }
            *reinterpret_cast<float4*>(pp + e4 * 4) = o;
        }
    }
}

// ---------------------------------------------------------------------------
// Kernel C (rewritten): MFMA bf16 FFN.
// Block = 256 thr (4 waves), tile = 64 positions = one (b,r), 64 consecutive c.
// LN -> bf16 A[64][64] in LDS -> GEMM1 (w1 frags from global) -> GELU ->
// g bf16 [64][256] in LDS -> GEMM2 (w2 frags from global) -> fp32 bounce tile
// -> coalesced stores along c with residual + b2.
// MFMA 16x16x32 bf16 layouts (verified m89):
//   A: lane l elem j -> A[l&15][(l>>4)*8 + j]
//   B: lane l elem j -> B[(l>>4)*8 + j][l&15]
//   D: lane l reg  i -> D[(l>>4)*4 + i][l&15]
// ---------------------------------------------------------------------------
#define SA 72    // s_a row stride in bf16 (pad 64+8)
#define SG 264   // s_g row stride in bf16 (pad 256+8)
#define SO 65    // s_o row stride in fp32 (pad 64+1)

__global__ __launch_bounds__(256) void ffn_mfma(
    const float* __restrict__ hbuf,
    const float* __restrict__ lng, const float* __restrict__ lnb,
    const float* __restrict__ w1, const float* __restrict__ b1,
    const float* __restrict__ w2, const float* __restrict__ b2,
    float* __restrict__ out)
{
    // smem map: [0, 33792) = s_g ; [33792, 50432) = s_a (9216B) then s_o (16640B)
    __shared__ __align__(16) char smem[33792 + 16640];
    short* s_g = (short*)smem;
    short* s_a = (short*)(smem + 33792);
    float* s_o = (float*)(smem + 33792);

    const int t = threadIdx.x;
    const int w = t >> 6;          // wave id 0..3
    const int l = t & 63;          // lane
    const int lr = l & 15;         // fragment row/col lane index
    const int lq = l >> 4;         // fragment k-group / row-group

    const int bid = blockIdx.x;
    const int cb  = bid & 7;
    const int rem = bid >> 3;
    const int r   = rem % R_;
    const int b   = rem / R_;
    const int c0  = cb * 64;

    // ---- phase 1: load 64 positions, LN, bf16 -> s_a -------------------
    {
        const int m  = t >> 2;     // position within tile
        const int qi = t & 3;      // quarter of the 64-float row
        const float* hp = hbuf + ((size_t)(b * C_ + c0 + m) * R_ + r) * E_ + qi * 16;
        const float4* hp4 = (const float4*)hp;
        float4 v0 = hp4[0], v1 = hp4[1], v2 = hp4[2], v3 = hp4[3];
        float hv[16];
        hv[0]=v0.x; hv[1]=v0.y; hv[2]=v0.z; hv[3]=v0.w;
        hv[4]=v1.x; hv[5]=v1.y; hv[6]=v1.z; hv[7]=v1.w;
        hv[8]=v2.x; hv[9]=v2.y; hv[10]=v2.z; hv[11]=v2.w;
        hv[12]=v3.x; hv[13]=v3.y; hv[14]=v3.z; hv[15]=v3.w;
        float s = 0.f, ss = 0.f;
        #pragma unroll
        for (int i = 0; i < 16; ++i) { s += hv[i]; ss += hv[i] * hv[i]; }
        s  += __shfl_xor(s, 1, 64);  s  += __shfl_xor(s, 2, 64);
        ss += __shfl_xor(ss, 1, 64); ss += __shfl_xor(ss, 2, 64);
        const float mu = s * (1.f / 64.f);
        const float rstd = rsqrtf(ss * (1.f / 64.f) - mu * mu + EPS);
        bf16x8 o0, o1;
        #pragma unroll
        for (int i = 0; i < 8; ++i) {
            const int e = qi * 16 + i;
            o0[i] = (short)f2bf((hv[i] - mu) * rstd * lng[e] + lnb[e]);
        }
        #pragma unroll
        for (int i = 0; i < 8; ++i) {
            const int e = qi * 16 + 8 + i;
            o1[i] = (short)f2bf((hv[8 + i] - mu) * rstd * lng[e] + lnb[e]);
        }
        *reinterpret_cast<bf16x8*>(&s_a[m * SA + qi * 16])     = o0;
        *reinterpret_cast<bf16x8*>(&s_a[m * SA + qi * 16 + 8]) = o1;
    }
    __syncthreads();

    // ---- GEMM1: D1[64][256] = A[64][64] x w1^T ; wave w owns n1 tiles 4w..4w+3
    {
        bf16x8 afr[4][2];
        #pragma unroll
        for (int mt = 0; mt < 4; ++mt)
            #pragma unroll
            for (int ks = 0; ks < 2; ++ks)
                afr[mt][ks] = *reinterpret_cast<const bf16x8*>(
                    &s_a[(mt * 16 + lr) * SA + ks * 32 + lq * 8]);

        #pragma unroll
        for (int nn = 0; nn < 4; ++nn) {
            const int n1 = w * 4 + nn;
            const int j  = n1 * 16 + lr;       // hidden index
            bf16x8 bfr[2];
            #pragma unroll
            for (int ks = 0; ks < 2; ++ks) {
                const float4* wp = (const float4*)(w1 + (size_t)j * 64 + ks * 32 + lq * 8);
                bfr[ks] = pack8(wp[0], wp[1]);
            }
            f32x4 acc[4];
            #pragma unroll
            for (int mt = 0; mt < 4; ++mt) { acc[mt][0]=0.f; acc[mt][1]=0.f; acc[mt][2]=0.f; acc[mt][3]=0.f; }
            #pragma unroll
            for (int ks = 0; ks < 2; ++ks)
                #pragma unroll
                for (int mt = 0; mt < 4; ++mt)
                    acc[mt] = __builtin_amdgcn_mfma_f32_16x16x32_bf16(afr[mt][ks], bfr[ks], acc[mt], 0, 0, 0);

            const float bj = b1[j];
            #pragma unroll
            for (int mt = 0; mt < 4; ++mt) {
                #pragma unroll
                for (int i = 0; i < 4; ++i) {
                    const float aa = acc[mt][i] + bj;
                    const float gl = 0.5f * aa * (1.f + erff(aa * 0.70710678118654752f));
                    const int mrow = mt * 16 + lq * 4 + i;
                    s_g[mrow * SG + j] = (short)f2bf(gl);
                }
            }
        }
    }
    __syncthreads();

    // ---- GEMM2: D2[64][64] = G[64][256] x w2^T ; wave w owns e-tile w ----
    {
        f32x4 acc2[4];
        #pragma unroll
        for (int mt = 0; mt < 4; ++mt) { acc2[mt][0]=0.f; acc2[mt][1]=0.f; acc2[mt][2]=0.f; acc2[mt][3]=0.f; }
        const int n = w * 16 + lr;             // output e index (col)
        #pragma unroll
        for (int ks = 0; ks < 8; ++ks) {
            const float4* wp = (const float4*)(w2 + (size_t)n * 256 + ks * 32 + lq * 8);
            const bf16x8 bfr = pack8(wp[0], wp[1]);
            #pragma unroll
            for (int mt = 0; mt < 4; ++mt) {
                const bf16x8 af = *reinterpret_cast<const bf16x8*>(
                    &s_g[(mt * 16 + lr) * SG + ks * 32 + lq * 8]);
                acc2[mt] = __builtin_amdgcn_mfma_f32_16x16x32_bf16(af, bfr, acc2[mt], 0, 0, 0);
            }
        }
        #pragma unroll
        for (int mt = 0; mt < 4; ++mt)
            #pragma unroll
            for (int i = 0; i < 4; ++i)
                s_o[(mt * 16 + lq * 4 + i) * SO + n] = acc2[mt][i];
    }
    __syncthreads();

    // ---- store phase: residual + b2, coalesced along c -------------------
    {
        const int m  = t & 63;                 // position (= lane)
        const int eb = (t >> 6) * 16;          // e block for this wave
        const int c  = c0 + m;
        const float* hp = hbuf + ((size_t)(b * C_ + c) * R_ + r) * E_ + eb;
        const float4* hp4 = (const float4*)hp;
        float4 v0 = hp4[0], v1 = hp4[1], v2 = hp4[2], v3 = hp4[3];
        float hv[16];
        hv[0]=v0.x; hv[1]=v0.y; hv[2]=v0.z; hv[3]=v0.w;
        hv[4]=v1.x; hv[5]=v1.y; hv[6]=v1.z; hv[7]=v1.w;
        hv[8]=v2.x; hv[9]=v2.y; hv[10]=v2.z; hv[11]=v2.w;
        hv[12]=v3.x; hv[13]=v3.y; hv[14]=v3.z; hv[15]=v3.w;
        #pragma unroll
        for (int i = 0; i < 16; ++i) {
            const int e = eb + i;
            const float val = s_o[m * SO + e] + b2[e] + hv[i];
            out[(((size_t)b * E_ + e) * R_ + r) * C_ + c] = val;
        }
    }
}

extern "C" void kernel_launch(void* const* d_in, const int* in_sizes, int n_in,
                              void* d_out, int out_size, void* d_ws, size_t ws_size,
                              hipStream_t stream) {
    const float* x      = (const float*)d_in[0];
    const float* row_wq = (const float*)d_in[1];
    const float* row_bq = (const float*)d_in[2];
    const float* row_wk = (const float*)d_in[3];
    const float* row_bk = (const float*)d_in[4];
    const float* row_wv = (const float*)d_in[5];
    const float* row_bv = (const float*)d_in[6];
    const float* row_wo = (const float*)d_in[7];
    const float* row_bo = (const float*)d_in[8];
    const float* col_wq = (const float*)d_in[9];
    const float* col_bq = (const float*)d_in[10];
    const float* col_wk = (const float*)d_in[11];
    const float* col_bk = (const float*)d_in[12];
    const float* col_wv = (const float*)d_in[13];
    const float* col_bv = (const float*)d_in[14];
    const float* col_wo = (const float*)d_in[15];
    const float* col_bo = (const float*)d_in[16];
    const float* rn_g   = (const float*)d_in[17];
    const float* rn_b   = (const float*)d_in[18];
    const float* cn_g   = (const float*)d_in[19];
    const float* cn_b   = (const float*)d_in[20];
    const float* fn_g   = (const float*)d_in[21];
    const float* fn_b   = (const float*)d_in[22];
    const float* w1     = (const float*)d_in[23];
    const float* b1     = (const float*)d_in[24];
    const float* w2     = (const float*)d_in[25];
    const float* b2     = (const float*)d_in[26];

    const size_t need = (size_t)B_ * C_ * R_ * E_ * sizeof(float);
    if (ws_size < need) return;
    float* hbuf = (float*)d_ws;

    row_attn<<<dim3(R_, B_), 512, 0, stream>>>(
        x, row_wq, row_bq, row_wk, row_bk, row_wv, row_bv, row_wo, row_bo,
        rn_g, rn_b, hbuf);
    col_attn<<<dim3(C_, B_), 256, 0, stream>>>(
        hbuf, col_wq, col_bq, col_wk, col_bk, col_wv, col_bv, col_wo, col_bo,
        cn_g, cn_b);
    ffn_mfma<<<B_ * R_ * 8, 256, 0, stream>>>(
        hbuf, fn_g, fn_b, w1, b1, w2, b2, (float*)d_out);
}

// Round 3
// 1438.952 us; speedup vs baseline: 2.7778x; 1.4684x over previous
//
#include <hip/hip_runtime.h>
#include <cmath>

#define E_ 64
#define H_ 4
#define B_ 2
#define R_ 1225
#define C_ 512
#define EPS 1e-5f

__device__ __forceinline__ float elu1(float a) { return a > 0.f ? a + 1.f : __expf(a); }

typedef float f32x4 __attribute__((ext_vector_type(4)));
typedef short bf16x8 __attribute__((ext_vector_type(8)));

__device__ __forceinline__ unsigned short f2bf(float f) {
    union { float f; unsigned u; } c; c.f = f;
    unsigned u = c.u + 0x7FFFu + ((c.u >> 16) & 1u);   // RNE
    return (unsigned short)(u >> 16);
}

__device__ __forceinline__ bf16x8 pack8(float4 a, float4 b) {
    bf16x8 r;
    r[0] = (short)f2bf(a.x); r[1] = (short)f2bf(a.y);
    r[2] = (short)f2bf(a.z); r[3] = (short)f2bf(a.w);
    r[4] = (short)f2bf(b.x); r[5] = (short)f2bf(b.y);
    r[6] = (short)f2bf(b.z); r[7] = (short)f2bf(b.w);
    return r;
}

// ---------------------------------------------------------------------------
// Shared attention structure:
//  per tile of 256 positions: thread t owns one position; LN -> xn (regs),
//  q/k scalar dots, write xn^T (bf16) + k (bf16) to LDS; then 4 waves
//  accumulate u[4][64] = K^T(4xN) * XN(Nx64) via mfma_f32_16x16x32_bf16:
//    A frag: lane l elem j -> A[l&15][(l>>4)*8+j]  (A = k^T, rows 4..15 zero)
//    B frag: lane l elem j -> B[(l>>4)*8+j][l&15]  (B = xn, so xn^T in LDS)
//    D     : lane l reg  i -> D[(l>>4)*4+i][l&15]
//  q kept in registers for pass 2 (no recompute).
// ---------------------------------------------------------------------------

#define SX 264   // s_xnT row stride (256+8) in bf16
// LDS ~44.7KB -> 3 blocks/CU

// ---------------------------------------------------------------------------
// Kernel A: row attention over c (length C=512) for each (b, r).
// Reads x in (B,E,R,C); writes h in (B,C,R,E). 256 threads, 2 tiles.
// ---------------------------------------------------------------------------
__global__ __launch_bounds__(256) void row_attn(
    const float* __restrict__ x,
    const float* __restrict__ wq, const float* __restrict__ bq,
    const float* __restrict__ wk, const float* __restrict__ bk,
    const float* __restrict__ wv, const float* __restrict__ bv,
    const float* __restrict__ wo, const float* __restrict__ bo,
    const float* __restrict__ lng, const float* __restrict__ lnb,
    float* __restrict__ hout)
{
    const int r = blockIdx.x;
    const int b = blockIdx.y;
    const int t = threadIdx.x;
    const int w = t >> 6;
    const int l = t & 63;
    const int lr = l & 15;
    const int lq = l >> 4;

    __shared__ short s_xnT[E_][SX];
    __shared__ short s_kb[16][SX];
    __shared__ float s_u[H_][E_];
    __shared__ float s_ktv[E_];
    __shared__ float s_wok[E_][H_];
    __shared__ float s_qm[H_];
    __shared__ float s_sk[H_];
    __shared__ float red_q[4][H_];
    __shared__ float red_k[4][H_];

    // zero k rows 4..15 (once)
    for (int i = t; i < 12 * SX; i += 256) (&s_kb[4][0])[i] = 0;

    const size_t RC = (size_t)R_ * C_;
    const float* xbase = x + (size_t)b * E_ * RC + (size_t)r * C_;

    float aq[H_] = {0.f, 0.f, 0.f, 0.f};
    float ak[H_] = {0.f, 0.f, 0.f, 0.f};
    float qs[2][H_];
    f32x4 uacc; uacc[0] = uacc[1] = uacc[2] = uacc[3] = 0.f;

    #pragma unroll
    for (int it = 0; it < 2; ++it) {
        const int c = it * 256 + t;
        const float* xp = xbase + c;
        float xv[E_];
        #pragma unroll
        for (int e = 0; e < E_; ++e) xv[e] = xp[(size_t)e * RC];
        float s = 0.f, ss = 0.f;
        #pragma unroll
        for (int e = 0; e < E_; ++e) { s += xv[e]; ss += xv[e] * xv[e]; }
        const float mu = s * (1.f / E_);
        const float rstd = rsqrtf(ss * (1.f / E_) - mu * mu + EPS);
        float xn[E_];
        #pragma unroll
        for (int e = 0; e < E_; ++e) xn[e] = (xv[e] - mu) * rstd * lng[e] + lnb[e];
        float k[H_];
        #pragma unroll
        for (int h = 0; h < H_; ++h) {
            float tq = bq[h], tk = bk[h];
            #pragma unroll
            for (int e = 0; e < E_; ++e) { tq += xn[e] * wq[h * E_ + e]; tk += xn[e] * wk[h * E_ + e]; }
            const float qv = elu1(tq); k[h] = elu1(tk);
            qs[it][h] = qv;
            aq[h] += qv; ak[h] += k[h];
        }
        #pragma unroll
        for (int e = 0; e < E_; ++e) s_xnT[e][t] = (short)f2bf(xn[e]);
        #pragma unroll
        for (int h = 0; h < H_; ++h) s_kb[h][t] = (short)f2bf(k[h]);
        __syncthreads();
        #pragma unroll
        for (int ks = 0; ks < 8; ++ks) {
            const bf16x8 af = *reinterpret_cast<const bf16x8*>(&s_kb[lr][ks * 32 + lq * 8]);
            const bf16x8 bf = *reinterpret_cast<const bf16x8*>(&s_xnT[w * 16 + lr][ks * 32 + lq * 8]);
            uacc = __builtin_amdgcn_mfma_f32_16x16x32_bf16(af, bf, uacc, 0, 0, 0);
        }
        __syncthreads();
    }

    if (lq == 0) {
        #pragma unroll
        for (int i = 0; i < 4; ++i) s_u[i][w * 16 + lr] = uacc[i];
    }
    #pragma unroll
    for (int h = 0; h < H_; ++h) {
        #pragma unroll
        for (int off = 32; off; off >>= 1) { aq[h] += __shfl_xor(aq[h], off, 64); ak[h] += __shfl_xor(ak[h], off, 64); }
    }
    if (l == 0) {
        #pragma unroll
        for (int h = 0; h < H_; ++h) { red_q[w][h] = aq[h]; red_k[w][h] = ak[h]; }
    }
    __syncthreads();
    if (t < H_) {
        float sq = 0.f, sk = 0.f;
        #pragma unroll
        for (int w2 = 0; w2 < 4; ++w2) { sq += red_q[w2][t]; sk += red_k[w2][t]; }
        s_qm[t] = sq * (1.f / C_);
        s_sk[t] = sk;
    }
    __syncthreads();
    if (t < E_) {
        const int h = t >> 4;
        float acc = 0.f;
        #pragma unroll
        for (int e = 0; e < E_; ++e) acc += wv[t * E_ + e] * s_u[h][e];
        s_ktv[t] = acc / s_sk[h] + bv[t];
    }
    __syncthreads();
    if (t < E_) {
        #pragma unroll
        for (int h = 0; h < H_; ++h) {
            float acc = 0.f;
            #pragma unroll
            for (int d = 0; d < 16; ++d) acc += wo[t * E_ + h * 16 + d] * s_ktv[h * 16 + d];
            s_wok[t][h] = acc;
        }
    }
    __syncthreads();

    #pragma unroll
    for (int it = 0; it < 2; ++it) {
        const int c = it * 256 + t;
        const float* xp = xbase + c;
        float qn[H_];
        #pragma unroll
        for (int h = 0; h < H_; ++h) qn[h] = qs[it][h] / s_qm[h];
        float* hp = hout + ((size_t)(b * C_ + c) * R_ + r) * E_;
        #pragma unroll
        for (int e4 = 0; e4 < 16; ++e4) {
            float4 o;
            float* ov = (float*)&o;
            #pragma unroll
            for (int i = 0; i < 4; ++i) {
                const int e = e4 * 4 + i;
                float tt = bo[e];
                #pragma unroll
                for (int h = 0; h < H_; ++h) tt += qn[h] * s_wok[e][h];
                ov[i] = xp[(size_t)e * RC] + tt;
            }
            *reinterpret_cast<float4*>(hp + e4 * 4) = o;
        }
    }
}

// ---------------------------------------------------------------------------
// Kernel B: col attention over r (length R=1225) for each (b, c). In-place.
// 256 threads, 5 tiles (last partial).
// ---------------------------------------------------------------------------
__global__ __launch_bounds__(256) void col_attn(
    float* __restrict__ hbuf,
    const float* __restrict__ wq, const float* __restrict__ bq,
    const float* __restrict__ wk, const float* __restrict__ bk,
    const float* __restrict__ wv, const float* __restrict__ bv,
    const float* __restrict__ wo, const float* __restrict__ bo,
    const float* __restrict__ lng, const float* __restrict__ lnb)
{
    const int c = blockIdx.x;
    const int b = blockIdx.y;
    const int t = threadIdx.x;
    const int w = t >> 6;
    const int l = t & 63;
    const int lr = l & 15;
    const int lq = l >> 4;

    __shared__ short s_xnT[E_][SX];
    __shared__ short s_kb[16][SX];
    __shared__ float s_u[H_][E_];
    __shared__ float s_ktv[E_];
    __shared__ float s_wok[E_][H_];
    __shared__ float s_qm[H_];
    __shared__ float s_sk[H_];
    __shared__ float red_q[4][H_];
    __shared__ float red_k[4][H_];

    for (int i = t; i < 12 * SX; i += 256) (&s_kb[4][0])[i] = 0;

    float* hp0 = hbuf + (size_t)(b * C_ + c) * R_ * E_;

    float aq[H_] = {0.f, 0.f, 0.f, 0.f};
    float ak[H_] = {0.f, 0.f, 0.f, 0.f};
    float qs[5][H_];
    f32x4 uacc; uacc[0] = uacc[1] = uacc[2] = uacc[3] = 0.f;

    #pragma unroll
    for (int it = 0; it < 5; ++it) {
        const int rr = it * 256 + t;
        const bool valid = (rr < R_);
        float xn[E_];
        float k[H_];
        if (valid) {
            const float* pp = hp0 + (size_t)rr * E_;
            float hv[E_];
            #pragma unroll
            for (int e4 = 0; e4 < 16; ++e4) {
                const float4 v4 = *reinterpret_cast<const float4*>(pp + e4 * 4);
                hv[e4 * 4 + 0] = v4.x; hv[e4 * 4 + 1] = v4.y;
                hv[e4 * 4 + 2] = v4.z; hv[e4 * 4 + 3] = v4.w;
            }
            float s = 0.f, ss = 0.f;
            #pragma unroll
            for (int e = 0; e < E_; ++e) { s += hv[e]; ss += hv[e] * hv[e]; }
            const float mu = s * (1.f / E_);
            const float rstd = rsqrtf(ss * (1.f / E_) - mu * mu + EPS);
            #pragma unroll
            for (int e = 0; e < E_; ++e) xn[e] = (hv[e] - mu) * rstd * lng[e] + lnb[e];
            #pragma unroll
            for (int h = 0; h < H_; ++h) {
                float tq = bq[h], tk = bk[h];
                #pragma unroll
                for (int e = 0; e < E_; ++e) { tq += xn[e] * wq[h * E_ + e]; tk += xn[e] * wk[h * E_ + e]; }
                const float qv = elu1(tq); k[h] = elu1(tk);
                qs[it][h] = qv;
                aq[h] += qv; ak[h] += k[h];
            }
        } else {
            #pragma unroll
            for (int e = 0; e < E_; ++e) xn[e] = 0.f;
            #pragma unroll
            for (int h = 0; h < H_; ++h) { k[h] = 0.f; qs[it][h] = 0.f; }
        }
        #pragma unroll
        for (int e = 0; e < E_; ++e) s_xnT[e][t] = (short)f2bf(xn[e]);
        #pragma unroll
        for (int h = 0; h < H_; ++h) s_kb[h][t] = (short)f2bf(k[h]);
        __syncthreads();
        #pragma unroll
        for (int ks = 0; ks < 8; ++ks) {
            const bf16x8 af = *reinterpret_cast<const bf16x8*>(&s_kb[lr][ks * 32 + lq * 8]);
            const bf16x8 bf = *reinterpret_cast<const bf16x8*>(&s_xnT[w * 16 + lr][ks * 32 + lq * 8]);
            uacc = __builtin_amdgcn_mfma_f32_16x16x32_bf16(af, bf, uacc, 0, 0, 0);
        }
        __syncthreads();
    }

    if (lq == 0) {
        #pragma unroll
        for (int i = 0; i < 4; ++i) s_u[i][w * 16 + lr] = uacc[i];
    }
    #pragma unroll
    for (int h = 0; h < H_; ++h) {
        #pragma unroll
        for (int off = 32; off; off >>= 1) { aq[h] += __shfl_xor(aq[h], off, 64); ak[h] += __shfl_xor(ak[h], off, 64); }
    }
    if (l == 0) {
        #pragma unroll
        for (int h = 0; h < H_; ++h) { red_q[w][h] = aq[h]; red_k[w][h] = ak[h]; }
    }
    __syncthreads();
    if (t < H_) {
        float sq = 0.f, sk = 0.f;
        #pragma unroll
        for (int w2 = 0; w2 < 4; ++w2) { sq += red_q[w2][t]; sk += red_k[w2][t]; }
        s_qm[t] = sq * (1.f / R_);
        s_sk[t] = sk;
    }
    __syncthreads();
    if (t < E_) {
        const int h = t >> 4;
        float acc = 0.f;
        #pragma unroll
        for (int e = 0; e < E_; ++e) acc += wv[t * E_ + e] * s_u[h][e];
        s_ktv[t] = acc / s_sk[h] + bv[t];
    }
    __syncthreads();
    if (t < E_) {
        #pragma unroll
        for (int h = 0; h < H_; ++h) {
            float acc = 0.f;
            #pragma unroll
            for (int d = 0; d < 16; ++d) acc += wo[t * E_ + h * 16 + d] * s_ktv[h * 16 + d];
            s_wok[t][h] = acc;
        }
    }
    __syncthreads();

    #pragma unroll
    for (int it = 0; it < 5; ++it) {
        const int rr = it * 256 + t;
        if (rr >= R_) continue;
        float qn[H_];
        #pragma unroll
        for (int h = 0; h < H_; ++h) qn[h] = qs[it][h] / s_qm[h];
        float* pp = hp0 + (size_t)rr * E_;
        #pragma unroll
        for (int e4 = 0; e4 < 16; ++e4) {
            const float4 v4 = *reinterpret_cast<const float4*>(pp + e4 * 4);
            const float* hv4 = (const float*)&v4;
            float4 o;
            float* ov = (float*)&o;
            #pragma unroll
            for (int i = 0; i < 4; ++i) {
                const int e = e4 * 4 + i;
                float tt = bo[e];
                #pragma unroll
                for (int h = 0; h < H_; ++h) tt += qn[h] * s_wok[e][h];
                ov[i] = hv4[i] + tt;
            }
            *reinterpret_cast<float4*>(pp + e4 * 4) = o;
        }
    }
}

// ---------------------------------------------------------------------------
// Kernel C: MFMA bf16 FFN (unchanged from round 2).
// ---------------------------------------------------------------------------
#define SA 72    // s_a row stride in bf16 (pad 64+8)
#define SG 264   // s_g row stride in bf16 (pad 256+8)
#define SO 65    // s_o row stride in fp32 (pad 64+1)

__global__ __launch_bounds__(256) void ffn_mfma(
    const float* __restrict__ hbuf,
    const float* __restrict__ lng, const float* __restrict__ lnb,
    const float* __restrict__ w1, const float* __restrict__ b1,
    const float* __restrict__ w2, const float* __restrict__ b2,
    float* __restrict__ out)
{
    __shared__ __align__(16) char smem[33792 + 16640];
    short* s_g = (short*)smem;
    short* s_a = (short*)(smem + 33792);
    float* s_o = (float*)(smem + 33792);

    const int t = threadIdx.x;
    const int w = t >> 6;
    const int l = t & 63;
    const int lr = l & 15;
    const int lq = l >> 4;

    const int bid = blockIdx.x;
    const int cb  = bid & 7;
    const int rem = bid >> 3;
    const int r   = rem % R_;
    const int b   = rem / R_;
    const int c0  = cb * 64;

    {
        const int m  = t >> 2;
        const int qi = t & 3;
        const float* hp = hbuf + ((size_t)(b * C_ + c0 + m) * R_ + r) * E_ + qi * 16;
        const float4* hp4 = (const float4*)hp;
        float4 v0 = hp4[0], v1 = hp4[1], v2 = hp4[2], v3 = hp4[3];
        float hv[16];
        hv[0]=v0.x; hv[1]=v0.y; hv[2]=v0.z; hv[3]=v0.w;
        hv[4]=v1.x; hv[5]=v1.y; hv[6]=v1.z; hv[7]=v1.w;
        hv[8]=v2.x; hv[9]=v2.y; hv[10]=v2.z; hv[11]=v2.w;
        hv[12]=v3.x; hv[13]=v3.y; hv[14]=v3.z; hv[15]=v3.w;
        float s = 0.f, ss = 0.f;
        #pragma unroll
        for (int i = 0; i < 16; ++i) { s += hv[i]; ss += hv[i] * hv[i]; }
        s  += __shfl_xor(s, 1, 64);  s  += __shfl_xor(s, 2, 64);
        ss += __shfl_xor(ss, 1, 64); ss += __shfl_xor(ss, 2, 64);
        const float mu = s * (1.f / 64.f);
        const float rstd = rsqrtf(ss * (1.f / 64.f) - mu * mu + EPS);
        bf16x8 o0, o1;
        #pragma unroll
        for (int i = 0; i < 8; ++i) {
            const int e = qi * 16 + i;
            o0[i] = (short)f2bf((hv[i] - mu) * rstd * lng[e] + lnb[e]);
        }
        #pragma unroll
        for (int i = 0; i < 8; ++i) {
            const int e = qi * 16 + 8 + i;
            o1[i] = (short)f2bf((hv[8 + i] - mu) * rstd * lng[e] + lnb[e]);
        }
        *reinterpret_cast<bf16x8*>(&s_a[m * SA + qi * 16])     = o0;
        *reinterpret_cast<bf16x8*>(&s_a[m * SA + qi * 16 + 8]) = o1;
    }
    __syncthreads();

    {
        bf16x8 afr[4][2];
        #pragma unroll
        for (int mt = 0; mt < 4; ++mt)
            #pragma unroll
            for (int ks = 0; ks < 2; ++ks)
                afr[mt][ks] = *reinterpret_cast<const bf16x8*>(
                    &s_a[(mt * 16 + lr) * SA + ks * 32 + lq * 8]);

        #pragma unroll
        for (int nn = 0; nn < 4; ++nn) {
            const int n1 = w * 4 + nn;
            const int j  = n1 * 16 + lr;
            bf16x8 bfr[2];
            #pragma unroll
            for (int ks = 0; ks < 2; ++ks) {
                const float4* wp = (const float4*)(w1 + (size_t)j * 64 + ks * 32 + lq * 8);
                bfr[ks] = pack8(wp[0], wp[1]);
            }
            f32x4 acc[4];
            #pragma unroll
            for (int mt = 0; mt < 4; ++mt) { acc[mt][0]=0.f; acc[mt][1]=0.f; acc[mt][2]=0.f; acc[mt][3]=0.f; }
            #pragma unroll
            for (int ks = 0; ks < 2; ++ks)
                #pragma unroll
                for (int mt = 0; mt < 4; ++mt)
                    acc[mt] = __builtin_amdgcn_mfma_f32_16x16x32_bf16(afr[mt][ks], bfr[ks], acc[mt], 0, 0, 0);

            const float bj = b1[j];
            #pragma unroll
            for (int mt = 0; mt < 4; ++mt) {
                #pragma unroll
                for (int i = 0; i < 4; ++i) {
                    const float aa = acc[mt][i] + bj;
                    const float gl = 0.5f * aa * (1.f + erff(aa * 0.70710678118654752f));
                    const int mrow = mt * 16 + lq * 4 + i;
                    s_g[mrow * SG + j] = (short)f2bf(gl);
                }
            }
        }
    }
    __syncthreads();

    {
        f32x4 acc2[4];
        #pragma unroll
        for (int mt = 0; mt < 4; ++mt) { acc2[mt][0]=0.f; acc2[mt][1]=0.f; acc2[mt][2]=0.f; acc2[mt][3]=0.f; }
        const int n = w * 16 + lr;
        #pragma unroll
        for (int ks = 0; ks < 8; ++ks) {
            const float4* wp = (const float4*)(w2 + (size_t)n * 256 + ks * 32 + lq * 8);
            const bf16x8 bfr = pack8(wp[0], wp[1]);
            #pragma unroll
            for (int mt = 0; mt < 4; ++mt) {
                const bf16x8 af = *reinterpret_cast<const bf16x8*>(
                    &s_g[(mt * 16 + lr) * SG + ks * 32 + lq * 8]);
                acc2[mt] = __builtin_amdgcn_mfma_f32_16x16x32_bf16(af, bfr, acc2[mt], 0, 0, 0);
            }
        }
        #pragma unroll
        for (int mt = 0; mt < 4; ++mt)
            #pragma unroll
            for (int i = 0; i < 4; ++i)
                s_o[(mt * 16 + lq * 4 + i) * SO + n] = acc2[mt][i];
    }
    __syncthreads();

    {
        const int m  = t & 63;
        const int eb = (t >> 6) * 16;
        const int c  = c0 + m;
        const float* hp = hbuf + ((size_t)(b * C_ + c) * R_ + r) * E_ + eb;
        const float4* hp4 = (const float4*)hp;
        float4 v0 = hp4[0], v1 = hp4[1], v2 = hp4[2], v3 = hp4[3];
        float hv[16];
        hv[0]=v0.x; hv[1]=v0.y; hv[2]=v0.z; hv[3]=v0.w;
        hv[4]=v1.x; hv[5]=v1.y; hv[6]=v1.z; hv[7]=v1.w;
        hv[8]=v2.x; hv[9]=v2.y; hv[10]=v2.z; hv[11]=v2.w;
        hv[12]=v3.x; hv[13]=v3.y; hv[14]=v3.z; hv[15]=v3.w;
        #pragma unroll
        for (int i = 0; i < 16; ++i) {
            const int e = eb + i;
            const float val = s_o[m * SO + e] + b2[e] + hv[i];
            out[(((size_t)b * E_ + e) * R_ + r) * C_ + c] = val;
        }
    }
}

extern "C" void kernel_launch(void* const* d_in, const int* in_sizes, int n_in,
                              void* d_out, int out_size, void* d_ws, size_t ws_size,
                              hipStream_t stream) {
    const float* x      = (const float*)d_in[0];
    const float* row_wq = (const float*)d_in[1];
    const float* row_bq = (const float*)d_in[2];
    const float* row_wk = (const float*)d_in[3];
    const float* row_bk = (const float*)d_in[4];
    const float* row_wv = (const float*)d_in[5];
    const float* row_bv = (const float*)d_in[6];
    const float* row_wo = (const float*)d_in[7];
    const float* row_bo = (const float*)d_in[8];
    const float* col_wq = (const float*)d_in[9];
    const float* col_bq = (const float*)d_in[10];
    const float* col_wk = (const float*)d_in[11];
    const float* col_bk = (const float*)d_in[12];
    const float* col_wv = (const float*)d_in[13];
    const float* col_bv = (const float*)d_in[14];
    const float* col_wo = (const float*)d_in[15];
    const float* col_bo = (const float*)d_in[16];
    const float* rn_g   = (const float*)d_in[17];
    const float* rn_b   = (const float*)d_in[18];
    const float* cn_g   = (const float*)d_in[19];
    const float* cn_b   = (const float*)d_in[20];
    const float* fn_g   = (const float*)d_in[21];
    const float* fn_b   = (const float*)d_in[22];
    const float* w1     = (const float*)d_in[23];
    const float* b1     = (const float*)d_in[24];
    const float* w2     = (const float*)d_in[25];
    const float* b2     = (const float*)d_in[26];

    const size_t need = (size_t)B_ * C_ * R_ * E_ * sizeof(float);
    if (ws_size < need) return;
    float* hbuf = (float*)d_ws;

    row_attn<<<dim3(R_, B_), 256, 0, stream>>>(
        x, row_wq, row_bq, row_wk, row_bk, row_wv, row_bv, row_wo, row_bo,
        rn_g, rn_b, hbuf);
    col_attn<<<dim3(C_, B_), 256, 0, stream>>>(
        hbuf, col_wq, col_bq, col_wk, col_bk, col_wv, col_bv, col_wo, col_bo,
        cn_g, cn_b);
    ffn_mfma<<<B_ * R_ * 8, 256, 0, stream>>>(
        hbuf, fn_g, fn_b, w1, b1, w2, b2, (float*)d_out);
}

// Round 4
// 1317.149 us; speedup vs baseline: 3.0347x; 1.0925x over previous
//
#include <hip/hip_runtime.h>
#include <cmath>

#define E_ 64
#define H_ 4
#define B_ 2
#define R_ 1225
#define C_ 512
#define EPS 1e-5f

__device__ __forceinline__ float elu1(float a) { return a > 0.f ? a + 1.f : __expf(a); }

typedef float f32x4 __attribute__((ext_vector_type(4)));
typedef short bf16x8 __attribute__((ext_vector_type(8)));
typedef short bf16x4 __attribute__((ext_vector_type(4)));

__device__ __forceinline__ unsigned short f2bf(float f) {
    union { float f; unsigned u; } c; c.f = f;
    unsigned u = c.u + 0x7FFFu + ((c.u >> 16) & 1u);   // RNE
    return (unsigned short)(u >> 16);
}

__device__ __forceinline__ bf16x8 pack8(float4 a, float4 b) {
    bf16x8 r;
    r[0] = (short)f2bf(a.x); r[1] = (short)f2bf(a.y);
    r[2] = (short)f2bf(a.z); r[3] = (short)f2bf(a.w);
    r[4] = (short)f2bf(b.x); r[5] = (short)f2bf(b.y);
    r[6] = (short)f2bf(b.z); r[7] = (short)f2bf(b.w);
    return r;
}

// tanh-approx GELU in sigmoid form: 0.5a(1+tanh(u)) = a*sigmoid(2u)
// max abs deviation from exact-erf GELU ~3e-4 (threshold headroom 0.113 vs 0.031)
__device__ __forceinline__ float gelu_fast(float a) {
    const float u = a * (-1.5957691216057308f - 0.0713548162726009f * a * a);
    return a / (1.f + __expf(u));
}

// ---------------------------------------------------------------------------
// Shared attention structure (unchanged from round 3).
// ---------------------------------------------------------------------------

#define SX 264   // s_xnT row stride (256+8) in bf16

__global__ __launch_bounds__(256) void row_attn(
    const float* __restrict__ x,
    const float* __restrict__ wq, const float* __restrict__ bq,
    const float* __restrict__ wk, const float* __restrict__ bk,
    const float* __restrict__ wv, const float* __restrict__ bv,
    const float* __restrict__ wo, const float* __restrict__ bo,
    const float* __restrict__ lng, const float* __restrict__ lnb,
    float* __restrict__ hout)
{
    const int r = blockIdx.x;
    const int b = blockIdx.y;
    const int t = threadIdx.x;
    const int w = t >> 6;
    const int l = t & 63;
    const int lr = l & 15;
    const int lq = l >> 4;

    __shared__ short s_xnT[E_][SX];
    __shared__ short s_kb[16][SX];
    __shared__ float s_u[H_][E_];
    __shared__ float s_ktv[E_];
    __shared__ float s_wok[E_][H_];
    __shared__ float s_qm[H_];
    __shared__ float s_sk[H_];
    __shared__ float red_q[4][H_];
    __shared__ float red_k[4][H_];

    for (int i = t; i < 12 * SX; i += 256) (&s_kb[4][0])[i] = 0;

    const size_t RC = (size_t)R_ * C_;
    const float* xbase = x + (size_t)b * E_ * RC + (size_t)r * C_;

    float aq[H_] = {0.f, 0.f, 0.f, 0.f};
    float ak[H_] = {0.f, 0.f, 0.f, 0.f};
    float qs[2][H_];
    f32x4 uacc; uacc[0] = uacc[1] = uacc[2] = uacc[3] = 0.f;

    #pragma unroll
    for (int it = 0; it < 2; ++it) {
        const int c = it * 256 + t;
        const float* xp = xbase + c;
        float xv[E_];
        #pragma unroll
        for (int e = 0; e < E_; ++e) xv[e] = xp[(size_t)e * RC];
        float s = 0.f, ss = 0.f;
        #pragma unroll
        for (int e = 0; e < E_; ++e) { s += xv[e]; ss += xv[e] * xv[e]; }
        const float mu = s * (1.f / E_);
        const float rstd = rsqrtf(ss * (1.f / E_) - mu * mu + EPS);
        float xn[E_];
        #pragma unroll
        for (int e = 0; e < E_; ++e) xn[e] = (xv[e] - mu) * rstd * lng[e] + lnb[e];
        float k[H_];
        #pragma unroll
        for (int h = 0; h < H_; ++h) {
            float tq = bq[h], tk = bk[h];
            #pragma unroll
            for (int e = 0; e < E_; ++e) { tq += xn[e] * wq[h * E_ + e]; tk += xn[e] * wk[h * E_ + e]; }
            const float qv = elu1(tq); k[h] = elu1(tk);
            qs[it][h] = qv;
            aq[h] += qv; ak[h] += k[h];
        }
        #pragma unroll
        for (int e = 0; e < E_; ++e) s_xnT[e][t] = (short)f2bf(xn[e]);
        #pragma unroll
        for (int h = 0; h < H_; ++h) s_kb[h][t] = (short)f2bf(k[h]);
        __syncthreads();
        #pragma unroll
        for (int ks = 0; ks < 8; ++ks) {
            const bf16x8 af = *reinterpret_cast<const bf16x8*>(&s_kb[lr][ks * 32 + lq * 8]);
            const bf16x8 bf = *reinterpret_cast<const bf16x8*>(&s_xnT[w * 16 + lr][ks * 32 + lq * 8]);
            uacc = __builtin_amdgcn_mfma_f32_16x16x32_bf16(af, bf, uacc, 0, 0, 0);
        }
        __syncthreads();
    }

    if (lq == 0) {
        #pragma unroll
        for (int i = 0; i < 4; ++i) s_u[i][w * 16 + lr] = uacc[i];
    }
    #pragma unroll
    for (int h = 0; h < H_; ++h) {
        #pragma unroll
        for (int off = 32; off; off >>= 1) { aq[h] += __shfl_xor(aq[h], off, 64); ak[h] += __shfl_xor(ak[h], off, 64); }
    }
    if (l == 0) {
        #pragma unroll
        for (int h = 0; h < H_; ++h) { red_q[w][h] = aq[h]; red_k[w][h] = ak[h]; }
    }
    __syncthreads();
    if (t < H_) {
        float sq = 0.f, sk = 0.f;
        #pragma unroll
        for (int w2 = 0; w2 < 4; ++w2) { sq += red_q[w2][t]; sk += red_k[w2][t]; }
        s_qm[t] = sq * (1.f / C_);
        s_sk[t] = sk;
    }
    __syncthreads();
    if (t < E_) {
        const int h = t >> 4;
        float acc = 0.f;
        #pragma unroll
        for (int e = 0; e < E_; ++e) acc += wv[t * E_ + e] * s_u[h][e];
        s_ktv[t] = acc / s_sk[h] + bv[t];
    }
    __syncthreads();
    if (t < E_) {
        #pragma unroll
        for (int h = 0; h < H_; ++h) {
            float acc = 0.f;
            #pragma unroll
            for (int d = 0; d < 16; ++d) acc += wo[t * E_ + h * 16 + d] * s_ktv[h * 16 + d];
            s_wok[t][h] = acc;
        }
    }
    __syncthreads();

    #pragma unroll
    for (int it = 0; it < 2; ++it) {
        const int c = it * 256 + t;
        const float* xp = xbase + c;
        float qn[H_];
        #pragma unroll
        for (int h = 0; h < H_; ++h) qn[h] = qs[it][h] / s_qm[h];
        float* hp = hout + ((size_t)(b * C_ + c) * R_ + r) * E_;
        #pragma unroll
        for (int e4 = 0; e4 < 16; ++e4) {
            float4 o;
            float* ov = (float*)&o;
            #pragma unroll
            for (int i = 0; i < 4; ++i) {
                const int e = e4 * 4 + i;
                float tt = bo[e];
                #pragma unroll
                for (int h = 0; h < H_; ++h) tt += qn[h] * s_wok[e][h];
                ov[i] = xp[(size_t)e * RC] + tt;
            }
            *reinterpret_cast<float4*>(hp + e4 * 4) = o;
        }
    }
}

__global__ __launch_bounds__(256) void col_attn(
    float* __restrict__ hbuf,
    const float* __restrict__ wq, const float* __restrict__ bq,
    const float* __restrict__ wk, const float* __restrict__ bk,
    const float* __restrict__ wv, const float* __restrict__ bv,
    const float* __restrict__ wo, const float* __restrict__ bo,
    const float* __restrict__ lng, const float* __restrict__ lnb)
{
    const int c = blockIdx.x;
    const int b = blockIdx.y;
    const int t = threadIdx.x;
    const int w = t >> 6;
    const int l = t & 63;
    const int lr = l & 15;
    const int lq = l >> 4;

    __shared__ short s_xnT[E_][SX];
    __shared__ short s_kb[16][SX];
    __shared__ float s_u[H_][E_];
    __shared__ float s_ktv[E_];
    __shared__ float s_wok[E_][H_];
    __shared__ float s_qm[H_];
    __shared__ float s_sk[H_];
    __shared__ float red_q[4][H_];
    __shared__ float red_k[4][H_];

    for (int i = t; i < 12 * SX; i += 256) (&s_kb[4][0])[i] = 0;

    float* hp0 = hbuf + (size_t)(b * C_ + c) * R_ * E_;

    float aq[H_] = {0.f, 0.f, 0.f, 0.f};
    float ak[H_] = {0.f, 0.f, 0.f, 0.f};
    float qs[5][H_];
    f32x4 uacc; uacc[0] = uacc[1] = uacc[2] = uacc[3] = 0.f;

    #pragma unroll
    for (int it = 0; it < 5; ++it) {
        const int rr = it * 256 + t;
        const bool valid = (rr < R_);
        float xn[E_];
        float k[H_];
        if (valid) {
            const float* pp = hp0 + (size_t)rr * E_;
            float hv[E_];
            #pragma unroll
            for (int e4 = 0; e4 < 16; ++e4) {
                const float4 v4 = *reinterpret_cast<const float4*>(pp + e4 * 4);
                hv[e4 * 4 + 0] = v4.x; hv[e4 * 4 + 1] = v4.y;
                hv[e4 * 4 + 2] = v4.z; hv[e4 * 4 + 3] = v4.w;
            }
            float s = 0.f, ss = 0.f;
            #pragma unroll
            for (int e = 0; e < E_; ++e) { s += hv[e]; ss += hv[e] * hv[e]; }
            const float mu = s * (1.f / E_);
            const float rstd = rsqrtf(ss * (1.f / E_) - mu * mu + EPS);
            #pragma unroll
            for (int e = 0; e < E_; ++e) xn[e] = (hv[e] - mu) * rstd * lng[e] + lnb[e];
            #pragma unroll
            for (int h = 0; h < H_; ++h) {
                float tq = bq[h], tk = bk[h];
                #pragma unroll
                for (int e = 0; e < E_; ++e) { tq += xn[e] * wq[h * E_ + e]; tk += xn[e] * wk[h * E_ + e]; }
                const float qv = elu1(tq); k[h] = elu1(tk);
                qs[it][h] = qv;
                aq[h] += qv; ak[h] += k[h];
            }
        } else {
            #pragma unroll
            for (int e = 0; e < E_; ++e) xn[e] = 0.f;
            #pragma unroll
            for (int h = 0; h < H_; ++h) { k[h] = 0.f; qs[it][h] = 0.f; }
        }
        #pragma unroll
        for (int e = 0; e < E_; ++e) s_xnT[e][t] = (short)f2bf(xn[e]);
        #pragma unroll
        for (int h = 0; h < H_; ++h) s_kb[h][t] = (short)f2bf(k[h]);
        __syncthreads();
        #pragma unroll
        for (int ks = 0; ks < 8; ++ks) {
            const bf16x8 af = *reinterpret_cast<const bf16x8*>(&s_kb[lr][ks * 32 + lq * 8]);
            const bf16x8 bf = *reinterpret_cast<const bf16x8*>(&s_xnT[w * 16 + lr][ks * 32 + lq * 8]);
            uacc = __builtin_amdgcn_mfma_f32_16x16x32_bf16(af, bf, uacc, 0, 0, 0);
        }
        __syncthreads();
    }

    if (lq == 0) {
        #pragma unroll
        for (int i = 0; i < 4; ++i) s_u[i][w * 16 + lr] = uacc[i];
    }
    #pragma unroll
    for (int h = 0; h < H_; ++h) {
        #pragma unroll
        for (int off = 32; off; off >>= 1) { aq[h] += __shfl_xor(aq[h], off, 64); ak[h] += __shfl_xor(ak[h], off, 64); }
    }
    if (l == 0) {
        #pragma unroll
        for (int h = 0; h < H_; ++h) { red_q[w][h] = aq[h]; red_k[w][h] = ak[h]; }
    }
    __syncthreads();
    if (t < H_) {
        float sq = 0.f, sk = 0.f;
        #pragma unroll
        for (int w2 = 0; w2 < 4; ++w2) { sq += red_q[w2][t]; sk += red_k[w2][t]; }
        s_qm[t] = sq * (1.f / R_);
        s_sk[t] = sk;
    }
    __syncthreads();
    if (t < E_) {
        const int h = t >> 4;
        float acc = 0.f;
        #pragma unroll
        for (int e = 0; e < E_; ++e) acc += wv[t * E_ + e] * s_u[h][e];
        s_ktv[t] = acc / s_sk[h] + bv[t];
    }
    __syncthreads();
    if (t < E_) {
        #pragma unroll
        for (int h = 0; h < H_; ++h) {
            float acc = 0.f;
            #pragma unroll
            for (int d = 0; d < 16; ++d) acc += wo[t * E_ + h * 16 + d] * s_ktv[h * 16 + d];
            s_wok[t][h] = acc;
        }
    }
    __syncthreads();

    #pragma unroll
    for (int it = 0; it < 5; ++it) {
        const int rr = it * 256 + t;
        if (rr >= R_) continue;
        float qn[H_];
        #pragma unroll
        for (int h = 0; h < H_; ++h) qn[h] = qs[it][h] / s_qm[h];
        float* pp = hp0 + (size_t)rr * E_;
        #pragma unroll
        for (int e4 = 0; e4 < 16; ++e4) {
            const float4 v4 = *reinterpret_cast<const float4*>(pp + e4 * 4);
            const float* hv4 = (const float*)&v4;
            float4 o;
            float* ov = (float*)&o;
            #pragma unroll
            for (int i = 0; i < 4; ++i) {
                const int e = e4 * 4 + i;
                float tt = bo[e];
                #pragma unroll
                for (int h = 0; h < H_; ++h) tt += qn[h] * s_wok[e][h];
                ov[i] = hv4[i] + tt;
            }
            *reinterpret_cast<float4*>(pp + e4 * 4) = o;
        }
    }
}

// ---------------------------------------------------------------------------
// prep_weights: one-shot fp32 -> bf16 conversion of w1 (256x64) and w2 (64x256)
// into the workspace tail (if it fits).
// ---------------------------------------------------------------------------
__global__ __launch_bounds__(256) void prep_weights(
    const float* __restrict__ w1, const float* __restrict__ w2,
    short* __restrict__ w1b, short* __restrict__ w2b)
{
    const int i = blockIdx.x * 256 + threadIdx.x;   // 0..32767
    if (i < 16384) w1b[i] = (short)f2bf(w1[i]);
    else           w2b[i - 16384] = (short)f2bf(w2[i - 16384]);
}

// ---------------------------------------------------------------------------
// Kernel C v2: MFMA bf16 FFN, swapped GEMM1 (D1^T = W1 x XN^T) so GELU
// results pack into ds_write_b64; fast GELU; bf16 weights loaded directly
// when PREP (else inline pack8 fallback).
// ---------------------------------------------------------------------------
#define SA 72    // s_a row stride in bf16 (pad 64+8)
#define SG 264   // s_g row stride in bf16 (pad 256+8)
#define SO 65    // s_o row stride in fp32 (pad 64+1)

template <bool PREP>
__global__ __launch_bounds__(256) void ffn_mfma(
    const float* __restrict__ hbuf,
    const float* __restrict__ lng, const float* __restrict__ lnb,
    const float* __restrict__ w1, const short* __restrict__ w1b,
    const float* __restrict__ b1,
    const float* __restrict__ w2, const short* __restrict__ w2b,
    const float* __restrict__ b2,
    float* __restrict__ out)
{
    __shared__ __align__(16) char smem[33792 + 16640];
    short* s_g = (short*)smem;
    short* s_a = (short*)(smem + 33792);
    float* s_o = (float*)(smem + 33792);

    const int t = threadIdx.x;
    const int w = t >> 6;
    const int l = t & 63;
    const int lr = l & 15;
    const int lq = l >> 4;

    const int bid = blockIdx.x;
    const int cb  = bid & 7;
    const int rem = bid >> 3;
    const int r   = rem % R_;
    const int b   = rem / R_;
    const int c0  = cb * 64;

    // ---- phase 1: load 64 positions, LN, bf16 -> s_a[m][e] ----------------
    {
        const int m  = t >> 2;
        const int qi = t & 3;
        const float* hp = hbuf + ((size_t)(b * C_ + c0 + m) * R_ + r) * E_ + qi * 16;
        const float4* hp4 = (const float4*)hp;
        float4 v0 = hp4[0], v1 = hp4[1], v2 = hp4[2], v3 = hp4[3];
        float hv[16];
        hv[0]=v0.x; hv[1]=v0.y; hv[2]=v0.z; hv[3]=v0.w;
        hv[4]=v1.x; hv[5]=v1.y; hv[6]=v1.z; hv[7]=v1.w;
        hv[8]=v2.x; hv[9]=v2.y; hv[10]=v2.z; hv[11]=v2.w;
        hv[12]=v3.x; hv[13]=v3.y; hv[14]=v3.z; hv[15]=v3.w;
        float s = 0.f, ss = 0.f;
        #pragma unroll
        for (int i = 0; i < 16; ++i) { s += hv[i]; ss += hv[i] * hv[i]; }
        s  += __shfl_xor(s, 1, 64);  s  += __shfl_xor(s, 2, 64);
        ss += __shfl_xor(ss, 1, 64); ss += __shfl_xor(ss, 2, 64);
        const float mu = s * (1.f / 64.f);
        const float rstd = rsqrtf(ss * (1.f / 64.f) - mu * mu + EPS);
        bf16x8 o0, o1;
        #pragma unroll
        for (int i = 0; i < 8; ++i) {
            const int e = qi * 16 + i;
            o0[i] = (short)f2bf((hv[i] - mu) * rstd * lng[e] + lnb[e]);
        }
        #pragma unroll
        for (int i = 0; i < 8; ++i) {
            const int e = qi * 16 + 8 + i;
            o1[i] = (short)f2bf((hv[8 + i] - mu) * rstd * lng[e] + lnb[e]);
        }
        *reinterpret_cast<bf16x8*>(&s_a[m * SA + qi * 16])     = o0;
        *reinterpret_cast<bf16x8*>(&s_a[m * SA + qi * 16 + 8]) = o1;
    }
    __syncthreads();

    // ---- GEMM1 (swapped): D1T[256][64] = W1 x XN^T ------------------------
    // A-frag = w1 rows (j), B-frag = s_a rows (m) -> lane holds 4 consecutive j
    // for one m => b64 packed GELU store into s_g[m][j].
    {
        bf16x8 bfr[4][2];              // B-frags, reused across all j-tiles
        #pragma unroll
        for (int mt = 0; mt < 4; ++mt)
            #pragma unroll
            for (int ks = 0; ks < 2; ++ks)
                bfr[mt][ks] = *reinterpret_cast<const bf16x8*>(
                    &s_a[(mt * 16 + lr) * SA + ks * 32 + lq * 8]);

        #pragma unroll
        for (int nn = 0; nn < 4; ++nn) {
            const int jt = w * 4 + nn;           // j-tile
            bf16x8 afr[2];
            if (PREP) {
                #pragma unroll
                for (int ks = 0; ks < 2; ++ks)
                    afr[ks] = *reinterpret_cast<const bf16x8*>(
                        w1b + (size_t)(jt * 16 + lr) * 64 + ks * 32 + lq * 8);
            } else {
                #pragma unroll
                for (int ks = 0; ks < 2; ++ks) {
                    const float4* wp = (const float4*)(w1 + (size_t)(jt * 16 + lr) * 64 + ks * 32 + lq * 8);
                    afr[ks] = pack8(wp[0], wp[1]);
                }
            }
            f32x4 acc[4];
            #pragma unroll
            for (int mt = 0; mt < 4; ++mt) { acc[mt][0]=0.f; acc[mt][1]=0.f; acc[mt][2]=0.f; acc[mt][3]=0.f; }
            #pragma unroll
            for (int ks = 0; ks < 2; ++ks)
                #pragma unroll
                for (int mt = 0; mt < 4; ++mt)
                    acc[mt] = __builtin_amdgcn_mfma_f32_16x16x32_bf16(afr[ks], bfr[mt][ks], acc[mt], 0, 0, 0);

            const float4 b1v = *reinterpret_cast<const float4*>(&b1[jt * 16 + lq * 4]);
            const float* b1p = (const float*)&b1v;
            #pragma unroll
            for (int mt = 0; mt < 4; ++mt) {
                const int m = mt * 16 + lr;
                bf16x4 pk;
                #pragma unroll
                for (int i = 0; i < 4; ++i) {
                    const float aa = acc[mt][i] + b1p[i];
                    pk[i] = (short)f2bf(gelu_fast(aa));
                }
                *reinterpret_cast<bf16x4*>(&s_g[m * SG + jt * 16 + lq * 4]) = pk;
            }
        }
    }
    __syncthreads();

    // ---- GEMM2: D2[64][64] = G[64][256] x w2^T ; wave w owns e-tile w -----
    {
        f32x4 acc2[4];
        #pragma unroll
        for (int mt = 0; mt < 4; ++mt) { acc2[mt][0]=0.f; acc2[mt][1]=0.f; acc2[mt][2]=0.f; acc2[mt][3]=0.f; }
        const int n = w * 16 + lr;
        #pragma unroll
        for (int ks = 0; ks < 8; ++ks) {
            bf16x8 bfr;
            if (PREP) {
                bfr = *reinterpret_cast<const bf16x8*>(w2b + (size_t)n * 256 + ks * 32 + lq * 8);
            } else {
                const float4* wp = (const float4*)(w2 + (size_t)n * 256 + ks * 32 + lq * 8);
                bfr = pack8(wp[0], wp[1]);
            }
            #pragma unroll
            for (int mt = 0; mt < 4; ++mt) {
                const bf16x8 af = *reinterpret_cast<const bf16x8*>(
                    &s_g[(mt * 16 + lr) * SG + ks * 32 + lq * 8]);
                acc2[mt] = __builtin_amdgcn_mfma_f32_16x16x32_bf16(af, bfr, acc2[mt], 0, 0, 0);
            }
        }
        #pragma unroll
        for (int mt = 0; mt < 4; ++mt)
            #pragma unroll
            for (int i = 0; i < 4; ++i)
                s_o[(mt * 16 + lq * 4 + i) * SO + n] = acc2[mt][i];
    }
    __syncthreads();

    // ---- store phase: residual + b2, coalesced along c --------------------
    {
        const int m  = t & 63;
        const int eb = (t >> 6) * 16;
        const int c  = c0 + m;
        const float* hp = hbuf + ((size_t)(b * C_ + c) * R_ + r) * E_ + eb;
        const float4* hp4 = (const float4*)hp;
        float4 v0 = hp4[0], v1 = hp4[1], v2 = hp4[2], v3 = hp4[3];
        float hv[16];
        hv[0]=v0.x; hv[1]=v0.y; hv[2]=v0.z; hv[3]=v0.w;
        hv[4]=v1.x; hv[5]=v1.y; hv[6]=v1.z; hv[7]=v1.w;
        hv[8]=v2.x; hv[9]=v2.y; hv[10]=v2.z; hv[11]=v2.w;
        hv[12]=v3.x; hv[13]=v3.y; hv[14]=v3.z; hv[15]=v3.w;
        #pragma unroll
        for (int i = 0; i < 16; ++i) {
            const int e = eb + i;
            const float val = s_o[m * SO + e] + b2[e] + hv[i];
            out[(((size_t)b * E_ + e) * R_ + r) * C_ + c] = val;
        }
    }
}

extern "C" void kernel_launch(void* const* d_in, const int* in_sizes, int n_in,
                              void* d_out, int out_size, void* d_ws, size_t ws_size,
                              hipStream_t stream) {
    const float* x      = (const float*)d_in[0];
    const float* row_wq = (const float*)d_in[1];
    const float* row_bq = (const float*)d_in[2];
    const float* row_wk = (const float*)d_in[3];
    const float* row_bk = (const float*)d_in[4];
    const float* row_wv = (const float*)d_in[5];
    const float* row_bv = (const float*)d_in[6];
    const float* row_wo = (const float*)d_in[7];
    const float* row_bo = (const float*)d_in[8];
    const float* col_wq = (const float*)d_in[9];
    const float* col_bq = (const float*)d_in[10];
    const float* col_wk = (const float*)d_in[11];
    const float* col_bk = (const float*)d_in[12];
    const float* col_wv = (const float*)d_in[13];
    const float* col_bv = (const float*)d_in[14];
    const float* col_wo = (const float*)d_in[15];
    const float* col_bo = (const float*)d_in[16];
    const float* rn_g   = (const float*)d_in[17];
    const float* rn_b   = (const float*)d_in[18];
    const float* cn_g   = (const float*)d_in[19];
    const float* cn_b   = (const float*)d_in[20];
    const float* fn_g   = (const float*)d_in[21];
    const float* fn_b   = (const float*)d_in[22];
    const float* w1     = (const float*)d_in[23];
    const float* b1     = (const float*)d_in[24];
    const float* w2     = (const float*)d_in[25];
    const float* b2     = (const float*)d_in[26];

    const size_t need = (size_t)B_ * C_ * R_ * E_ * sizeof(float);
    if (ws_size < need) return;
    float* hbuf = (float*)d_ws;

    const bool prep = (ws_size >= need + 2 * 16384 * sizeof(short) + 256);
    short* w1b = (short*)((char*)d_ws + need);
    short* w2b = w1b + 16384;

    row_attn<<<dim3(R_, B_), 256, 0, stream>>>(
        x, row_wq, row_bq, row_wk, row_bk, row_wv, row_bv, row_wo, row_bo,
        rn_g, rn_b, hbuf);
    col_attn<<<dim3(C_, B_), 256, 0, stream>>>(
        hbuf, col_wq, col_bq, col_wk, col_bk, col_wv, col_bv, col_wo, col_bo,
        cn_g, cn_b);
    if (prep) {
        prep_weights<<<128, 256, 0, stream>>>(w1, w2, w1b, w2b);
        ffn_mfma<true><<<B_ * R_ * 8, 256, 0, stream>>>(
            hbuf, fn_g, fn_b, w1, w1b, b1, w2, w2b, b2, (float*)d_out);
    } else {
        ffn_mfma<false><<<B_ * R_ * 8, 256, 0, stream>>>(
            hbuf, fn_g, fn_b, w1, w1b, b1, w2, w2b, b2, (float*)d_out);
    }
}